// Round 3
// baseline (473.039 us; speedup 1.0000x reference)
//
#include <hip/hip_runtime.h>
#include <hip/hip_cooperative_groups.h>

namespace cg = cooperative_groups;

#define VR 4
#define NVOX 64            // VR^3
#define NCLS 40
#define NB 64
#define NPTS 100000
#define BPB 16             // blocks per batch
#define GRID (NB * BPB)    // 1024 blocks, fits co-resident (8 blocks/CU x 256 CU)
#define G_PER_B (NPTS / 4)        // 25000 groups of 4 points (= 3 float4 each)
#define F4_PER_B (NPTS * 3 / 4)   // 75000 float4 per batch
#define STRIDE_G (BPB * 256)      // 4096 groups per grid-stride step
#define FLT_BIG 3.402823466e38f

__device__ __forceinline__ int bin1(float v, float mn, float s4) {
    int i = (int)((v - mn) * s4);   // v>=mn, s4>0 -> trunc==floor
    return i > (VR - 1) ? (VR - 1) : i;
}

__device__ __forceinline__ void tally(int v, unsigned long long vm,
                                      const unsigned long long* ns,
                                      unsigned& cnt) {
    unsigned long long b0 = __ballot(v & 1);
    unsigned long long b1 = __ballot(v & 2);
    unsigned long long b2 = __ballot(v & 4);
    unsigned long long b3 = __ballot(v & 8);
    unsigned long long b4 = __ballot(v & 16);
    unsigned long long b5 = __ballot(v & 32);
    unsigned long long m = vm & (b0 ^ ns[0]) & (b1 ^ ns[1]) & (b2 ^ ns[2])
                              & (b3 ^ ns[3]) & (b4 ^ ns[4]) & (b5 ^ ns[5]);
    cnt += (unsigned)__popcll(m);
}

// One cooperative kernel: minmax -> grid.sync -> ballot-hist -> grid.sync ->
// reduce + GEMV (first 64 blocks). No atomics anywhere; all ws slots are
// unconditionally overwritten each call.
__global__ __launch_bounds__(256) void fused_k(const float4* __restrict__ x,
                                               float* __restrict__ pmin,
                                               float* __restrict__ pmax,
                                               unsigned* __restrict__ phist,
                                               const float* __restrict__ W,
                                               const float* __restrict__ bias,
                                               float* __restrict__ out) {
    cg::grid_group grid = cg::this_grid();
    const int b = blockIdx.x / BPB;
    const int sub = blockIdx.x % BPB;
    const float4* xb = x + (size_t)b * F4_PER_B;
    const int lane = threadIdx.x & 63;
    const int wv = threadIdx.x >> 6;

    // ---------------- phase 1: per-block partial min/max --------------------
    {
        float mn0 = FLT_BIG, mn1 = FLT_BIG, mn2 = FLT_BIG;
        float mx0 = -FLT_BIG, mx1 = -FLT_BIG, mx2 = -FLT_BIG;

        for (int base = sub * 256; base < G_PER_B; base += STRIDE_G) {
            int g = base + (int)threadIdx.x;
            bool valid = g < G_PER_B;
            int gc = valid ? g : (G_PER_B - 1);
            float4 a = xb[3 * gc];
            float4 c = xb[3 * gc + 1];
            float4 e = xb[3 * gc + 2];
            if (valid) {
                // flat%3: a.x->0 a.y->1 a.z->2 a.w->0 c.x->1 c.y->2
                //         c.z->0 c.w->1 e.x->2 e.y->0 e.z->1 e.w->2
                mn0 = fminf(mn0, fminf(fminf(a.x, a.w), fminf(c.z, e.y)));
                mx0 = fmaxf(mx0, fmaxf(fmaxf(a.x, a.w), fmaxf(c.z, e.y)));
                mn1 = fminf(mn1, fminf(fminf(a.y, c.x), fminf(c.w, e.z)));
                mx1 = fmaxf(mx1, fmaxf(fmaxf(a.y, c.x), fmaxf(c.w, e.z)));
                mn2 = fminf(mn2, fminf(fminf(a.z, c.y), fminf(e.x, e.w)));
                mx2 = fmaxf(mx2, fmaxf(fmaxf(a.z, c.y), fmaxf(e.x, e.w)));
            }
        }

        #pragma unroll
        for (int off = 32; off > 0; off >>= 1) {
            mn0 = fminf(mn0, __shfl_down(mn0, off, 64));
            mn1 = fminf(mn1, __shfl_down(mn1, off, 64));
            mn2 = fminf(mn2, __shfl_down(mn2, off, 64));
            mx0 = fmaxf(mx0, __shfl_down(mx0, off, 64));
            mx1 = fmaxf(mx1, __shfl_down(mx1, off, 64));
            mx2 = fmaxf(mx2, __shfl_down(mx2, off, 64));
        }

        __shared__ float smn[4][3], smx[4][3];
        if (lane == 0) {
            smn[wv][0] = mn0; smn[wv][1] = mn1; smn[wv][2] = mn2;
            smx[wv][0] = mx0; smx[wv][1] = mx1; smx[wv][2] = mx2;
        }
        __syncthreads();
        if (threadIdx.x < 3) {
            const int d = threadIdx.x;
            float a = smn[0][d], z = smx[0][d];
            #pragma unroll
            for (int w = 1; w < 4; w++) {
                a = fminf(a, smn[w][d]);
                z = fmaxf(z, smx[w][d]);
            }
            pmin[(b * BPB + sub) * 3 + d] = a;
            pmax[(b * BPB + sub) * 3 + d] = z;
        }
    }

    __threadfence();
    grid.sync();

    // ---------------- phase 2: ballot histogram -----------------------------
    {
        __shared__ float smm[6];   // mn0 mn1 mn2 mx0 mx1 mx2
        if (threadIdx.x < 6) {
            int d = threadIdx.x % 3;
            bool isMax = threadIdx.x >= 3;
            float r = isMax ? -FLT_BIG : FLT_BIG;
            for (int s = 0; s < BPB; s++) {
                float v = isMax ? pmax[(b * BPB + s) * 3 + d]
                                : pmin[(b * BPB + s) * 3 + d];
                r = isMax ? fmaxf(r, v) : fminf(r, v);
            }
            smm[threadIdx.x] = r;
        }
        __syncthreads();
        const float mn_0 = smm[0], mn_1 = smm[1], mn_2 = smm[2];
        const float s4_0 = (float)VR / (smm[3] - smm[0]);
        const float s4_1 = (float)VR / (smm[4] - smm[1]);
        const float s4_2 = (float)VR / (smm[5] - smm[2]);

        unsigned long long ns[6];
        #pragma unroll
        for (int k = 0; k < 6; k++)
            ns[k] = ((lane >> k) & 1) ? 0ull : ~0ull;

        unsigned cnt = 0;
        for (int base = sub * 256; base < G_PER_B; base += STRIDE_G) {
            int g = base + (int)threadIdx.x;
            bool valid = g < G_PER_B;
            int gc = valid ? g : (G_PER_B - 1);
            float4 a = xb[3 * gc];
            float4 c = xb[3 * gc + 1];
            float4 e = xb[3 * gc + 2];
            unsigned long long vm = __ballot(valid);
            // points: (a.x,a.y,a.z) (a.w,c.x,c.y) (c.z,c.w,e.x) (e.y,e.z,e.w)
            int v0 = bin1(a.x, mn_0, s4_0) * 16 + bin1(a.y, mn_1, s4_1) * 4 + bin1(a.z, mn_2, s4_2);
            int v1 = bin1(a.w, mn_0, s4_0) * 16 + bin1(c.x, mn_1, s4_1) * 4 + bin1(c.y, mn_2, s4_2);
            int v2 = bin1(c.z, mn_0, s4_0) * 16 + bin1(c.w, mn_1, s4_1) * 4 + bin1(e.x, mn_2, s4_2);
            int v3 = bin1(e.y, mn_0, s4_0) * 16 + bin1(e.z, mn_1, s4_1) * 4 + bin1(e.w, mn_2, s4_2);
            tally(v0, vm, ns, cnt);
            tally(v1, vm, ns, cnt);
            tally(v2, vm, ns, cnt);
            tally(v3, vm, ns, cnt);
        }

        __shared__ unsigned swh[4][NVOX];
        swh[wv][lane] = cnt;
        __syncthreads();
        if (threadIdx.x < NVOX) {
            phist[(b * BPB + sub) * NVOX + threadIdx.x] =
                swh[0][threadIdx.x] + swh[1][threadIdx.x] +
                swh[2][threadIdx.x] + swh[3][threadIdx.x];
        }
    }

    __threadfence();
    grid.sync();

    // ---------------- phase 3: reduce partial hists + GEMV ------------------
    if (blockIdx.x < NB) {
        const int bb = blockIdx.x;
        __shared__ float fh[NVOX];
        __shared__ float sW[NCLS * NVOX];

        if (threadIdx.x < NVOX) {
            unsigned s = 0;
            for (int p = 0; p < BPB; p++)
                s += phist[(bb * BPB + p) * NVOX + threadIdx.x];
            fh[threadIdx.x] = (float)s * (1.0f / (float)NPTS);
        }
        for (int i = threadIdx.x; i < NCLS * NVOX; i += 256)
            sW[i] = W[i];
        __syncthreads();

        if (threadIdx.x < NCLS) {
            const int c = threadIdx.x;
            float acc = 0.f;
            #pragma unroll
            for (int f = 0; f < NVOX; f++)
                acc += fh[f] * sW[c * NVOX + f];
            out[bb * NCLS + c] = acc + bias[c];
        }
    }
}

extern "C" void kernel_launch(void* const* d_in, const int* in_sizes, int n_in,
                              void* d_out, int out_size, void* d_ws, size_t ws_size,
                              hipStream_t stream) {
    const float4* x = (const float4*)d_in[0];    // (64, 100000, 3) fp32
    const float* W = (const float*)d_in[1];      // (40, 64) fp32
    const float* bias = (const float*)d_in[2];   // (40,) fp32
    float* out = (float*)d_out;                  // (64, 40) fp32

    // ws layout (all slots fully overwritten every call -> no init needed):
    float* pmin = (float*)d_ws;                      // NB*BPB*3 f32
    float* pmax = pmin + NB * BPB * 3;               // NB*BPB*3 f32
    unsigned* phist = (unsigned*)(pmax + NB * BPB * 3);  // NB*BPB*64 u32

    void* args[] = {(void*)&x, (void*)&pmin, (void*)&pmax, (void*)&phist,
                    (void*)&W, (void*)&bias, (void*)&out};
    hipLaunchCooperativeKernel((void*)fused_k, dim3(GRID), dim3(256), args, 0,
                               stream);
}

// Round 4
// 168.669 us; speedup vs baseline: 2.8045x; 2.8045x over previous
//
#include <hip/hip_runtime.h>

#define VR 4
#define NVOX 64            // VR^3
#define NCLS 40
#define NB 64
#define NPTS 100000
#define BPB 16             // blocks per batch
#define G_PER_B (NPTS / 4)        // 25000 groups of 4 points (= 3 float4 each)
#define F4_PER_B (NPTS * 3 / 4)   // 75000 float4 per batch
#define STRIDE_G (BPB * 256)      // 4096 groups per grid-stride step
#define FLT_BIG 3.402823466e38f

// ---------------------------------------------------------------------------
// Pass 1: per-batch per-dim min/max -> private partial slots (no atomics, no
// init needed). Also zero-initializes the per-batch completion counters used
// by pass 2's last-block-done tail (ws arrives poisoned 0xAA).
// ---------------------------------------------------------------------------
__global__ __launch_bounds__(256) void minmax_k(const float4* __restrict__ x,
                                                float* __restrict__ pmin,
                                                float* __restrict__ pmax,
                                                unsigned* __restrict__ cnt) {
    const int b = blockIdx.x / BPB;
    const int sub = blockIdx.x % BPB;
    const float4* xb = x + (size_t)b * F4_PER_B;

    if (sub == 0 && threadIdx.x == 0) cnt[b] = 0;  // visible to hist_k via kernel boundary

    float mn0 = FLT_BIG, mn1 = FLT_BIG, mn2 = FLT_BIG;
    float mx0 = -FLT_BIG, mx1 = -FLT_BIG, mx2 = -FLT_BIG;

    for (int base = sub * 256; base < G_PER_B; base += STRIDE_G) {
        int g = base + (int)threadIdx.x;
        bool valid = g < G_PER_B;
        int gc = valid ? g : (G_PER_B - 1);
        float4 a = xb[3 * gc];
        float4 c = xb[3 * gc + 1];
        float4 e = xb[3 * gc + 2];
        if (valid) {
            // flat%3: a.x->0 a.y->1 a.z->2 a.w->0 c.x->1 c.y->2
            //         c.z->0 c.w->1 e.x->2 e.y->0 e.z->1 e.w->2
            mn0 = fminf(mn0, fminf(fminf(a.x, a.w), fminf(c.z, e.y)));
            mx0 = fmaxf(mx0, fmaxf(fmaxf(a.x, a.w), fmaxf(c.z, e.y)));
            mn1 = fminf(mn1, fminf(fminf(a.y, c.x), fminf(c.w, e.z)));
            mx1 = fmaxf(mx1, fmaxf(fmaxf(a.y, c.x), fmaxf(c.w, e.z)));
            mn2 = fminf(mn2, fminf(fminf(a.z, c.y), fminf(e.x, e.w)));
            mx2 = fmaxf(mx2, fmaxf(fmaxf(a.z, c.y), fmaxf(e.x, e.w)));
        }
    }

    #pragma unroll
    for (int off = 32; off > 0; off >>= 1) {
        mn0 = fminf(mn0, __shfl_down(mn0, off, 64));
        mn1 = fminf(mn1, __shfl_down(mn1, off, 64));
        mn2 = fminf(mn2, __shfl_down(mn2, off, 64));
        mx0 = fmaxf(mx0, __shfl_down(mx0, off, 64));
        mx1 = fmaxf(mx1, __shfl_down(mx1, off, 64));
        mx2 = fmaxf(mx2, __shfl_down(mx2, off, 64));
    }

    __shared__ float smn[4][3], smx[4][3];
    const int lane = threadIdx.x & 63;
    const int wv = threadIdx.x >> 6;
    if (lane == 0) {
        smn[wv][0] = mn0; smn[wv][1] = mn1; smn[wv][2] = mn2;
        smx[wv][0] = mx0; smx[wv][1] = mx1; smx[wv][2] = mx2;
    }
    __syncthreads();
    if (threadIdx.x < 3) {
        const int d = threadIdx.x;
        float a = smn[0][d], z = smx[0][d];
        #pragma unroll
        for (int w = 1; w < 4; w++) {
            a = fminf(a, smn[w][d]);
            z = fmaxf(z, smx[w][d]);
        }
        pmin[(b * BPB + sub) * 3 + d] = a;
        pmax[(b * BPB + sub) * 3 + d] = z;
    }
}

// ---------------------------------------------------------------------------
// Pass 2: ballot histogram (lane L of each wave owns voxel L's count; zero
// atomics in the hot loop, distribution-independent). Tail: last block of
// each batch (device-scope atomic counter) reduces the 16 partials and does
// the 40x64 GEMV — removes the third dispatch.
// ---------------------------------------------------------------------------
__device__ __forceinline__ int bin1(float v, float mn, float s4) {
    int i = (int)((v - mn) * s4);   // v>=mn, s4>0 -> trunc==floor
    return i > (VR - 1) ? (VR - 1) : i;
}

__device__ __forceinline__ void tally(int v, unsigned long long vm,
                                      const unsigned long long* ns,
                                      unsigned& cnt) {
    unsigned long long b0 = __ballot(v & 1);
    unsigned long long b1 = __ballot(v & 2);
    unsigned long long b2 = __ballot(v & 4);
    unsigned long long b3 = __ballot(v & 8);
    unsigned long long b4 = __ballot(v & 16);
    unsigned long long b5 = __ballot(v & 32);
    unsigned long long m = vm & (b0 ^ ns[0]) & (b1 ^ ns[1]) & (b2 ^ ns[2])
                              & (b3 ^ ns[3]) & (b4 ^ ns[4]) & (b5 ^ ns[5]);
    cnt += (unsigned)__popcll(m);
}

__global__ __launch_bounds__(256) void hist_k(const float4* __restrict__ x,
                                              const float* __restrict__ pmin,
                                              const float* __restrict__ pmax,
                                              unsigned* __restrict__ phist,
                                              unsigned* __restrict__ cnt,
                                              const float* __restrict__ W,
                                              const float* __restrict__ bias,
                                              float* __restrict__ out) {
    const int b = blockIdx.x / BPB;
    const int sub = blockIdx.x % BPB;
    const float4* xb = x + (size_t)b * F4_PER_B;
    const int lane = threadIdx.x & 63;
    const int wv = threadIdx.x >> 6;

    // reduce the 16 min/max partials for this batch
    __shared__ float smm[6];   // mn0 mn1 mn2 mx0 mx1 mx2
    if (threadIdx.x < 6) {
        int d = threadIdx.x % 3;
        bool isMax = threadIdx.x >= 3;
        float r = isMax ? -FLT_BIG : FLT_BIG;
        for (int s = 0; s < BPB; s++) {
            float v = isMax ? pmax[(b * BPB + s) * 3 + d]
                            : pmin[(b * BPB + s) * 3 + d];
            r = isMax ? fmaxf(r, v) : fminf(r, v);
        }
        smm[threadIdx.x] = r;
    }
    __syncthreads();
    const float mn_0 = smm[0], mn_1 = smm[1], mn_2 = smm[2];
    const float s4_0 = (float)VR / (smm[3] - smm[0]);
    const float s4_1 = (float)VR / (smm[4] - smm[1]);
    const float s4_2 = (float)VR / (smm[5] - smm[2]);

    unsigned long long ns[6];
    #pragma unroll
    for (int k = 0; k < 6; k++)
        ns[k] = ((lane >> k) & 1) ? 0ull : ~0ull;

    unsigned c_ = 0;
    for (int base = sub * 256; base < G_PER_B; base += STRIDE_G) {
        int g = base + (int)threadIdx.x;
        bool valid = g < G_PER_B;
        int gc = valid ? g : (G_PER_B - 1);
        float4 a = xb[3 * gc];
        float4 c = xb[3 * gc + 1];
        float4 e = xb[3 * gc + 2];
        unsigned long long vm = __ballot(valid);
        // points: (a.x,a.y,a.z) (a.w,c.x,c.y) (c.z,c.w,e.x) (e.y,e.z,e.w)
        int v0 = bin1(a.x, mn_0, s4_0) * 16 + bin1(a.y, mn_1, s4_1) * 4 + bin1(a.z, mn_2, s4_2);
        int v1 = bin1(a.w, mn_0, s4_0) * 16 + bin1(c.x, mn_1, s4_1) * 4 + bin1(c.y, mn_2, s4_2);
        int v2 = bin1(c.z, mn_0, s4_0) * 16 + bin1(c.w, mn_1, s4_1) * 4 + bin1(e.x, mn_2, s4_2);
        int v3 = bin1(e.y, mn_0, s4_0) * 16 + bin1(e.z, mn_1, s4_1) * 4 + bin1(e.w, mn_2, s4_2);
        tally(v0, vm, ns, c_);
        tally(v1, vm, ns, c_);
        tally(v2, vm, ns, c_);
        tally(v3, vm, ns, c_);
    }

    __shared__ unsigned swh[4][NVOX];
    swh[wv][lane] = c_;
    __syncthreads();
    if (threadIdx.x < NVOX) {
        phist[(b * BPB + sub) * NVOX + threadIdx.x] =
            swh[0][threadIdx.x] + swh[1][threadIdx.x] +
            swh[2][threadIdx.x] + swh[3][threadIdx.x];
    }

    // ---- last-block-done tail: reduce partials + GEMV for this batch ------
    __shared__ unsigned s_last;
    __syncthreads();                 // phist stores issued by all threads
    if (threadIdx.x == 0) {
        __threadfence();             // release our phist partial device-wide
        s_last = atomicAdd(&cnt[b], 1u);  // device-scope
    }
    __syncthreads();
    if (s_last != BPB - 1) return;   // only the last arriver continues
    __threadfence();                 // acquire: other blocks' phist now visible

    __shared__ float fh[NVOX];
    __shared__ float sW[NCLS * NVOX];
    if (threadIdx.x < NVOX) {
        unsigned s = 0;
        for (int p = 0; p < BPB; p++)
            s += phist[(b * BPB + p) * NVOX + threadIdx.x];
        fh[threadIdx.x] = (float)s * (1.0f / (float)NPTS);
    }
    for (int i = threadIdx.x; i < NCLS * NVOX; i += 256)
        sW[i] = W[i];
    __syncthreads();
    if (threadIdx.x < NCLS) {
        const int cc = threadIdx.x;
        float acc = 0.f;
        #pragma unroll
        for (int f = 0; f < NVOX; f++)
            acc += fh[f] * sW[cc * NVOX + f];
        out[b * NCLS + cc] = acc + bias[cc];
    }
}

extern "C" void kernel_launch(void* const* d_in, const int* in_sizes, int n_in,
                              void* d_out, int out_size, void* d_ws, size_t ws_size,
                              hipStream_t stream) {
    const float* x = (const float*)d_in[0];      // (64, 100000, 3) fp32
    const float* W = (const float*)d_in[1];      // (40, 64) fp32
    const float* bias = (const float*)d_in[2];   // (40,) fp32
    float* out = (float*)d_out;                  // (64, 40) fp32

    // ws layout:
    //   pmin  : NB*BPB*3 f32   (fully overwritten by minmax_k)
    //   pmax  : NB*BPB*3 f32   (fully overwritten by minmax_k)
    //   phist : NB*BPB*64 u32  (fully overwritten by hist_k)
    //   cnt   : NB u32         (zeroed by minmax_k, used by hist_k tail)
    float* pmin = (float*)d_ws;
    float* pmax = pmin + NB * BPB * 3;
    unsigned* phist = (unsigned*)(pmax + NB * BPB * 3);
    unsigned* cnt = phist + NB * BPB * NVOX;

    minmax_k<<<NB * BPB, 256, 0, stream>>>((const float4*)x, pmin, pmax, cnt);
    hist_k<<<NB * BPB, 256, 0, stream>>>((const float4*)x, pmin, pmax, phist,
                                         cnt, W, bias, out);
}

// Round 5
// 131.216 us; speedup vs baseline: 3.6051x; 1.2854x over previous
//
#include <hip/hip_runtime.h>

#define VR 4
#define NVOX 64            // VR^3
#define NCLS 40
#define NB 64
#define NPTS 100000
#define BPB 25             // blocks per batch
#define GPB 1000           // groups per block (25000 / 25)
#define ATH 250            // active threads per block (250 * 4 groups = 1000)
#define G_PER_B (NPTS / 4)        // 25000 groups of 4 points (3 float4 each)
#define F4_PER_B (NPTS * 3 / 4)   // 75000 float4 per batch
#define FLT_BIG 3.402823466e38f

// ---------------------------------------------------------------------------
// Pass 1: per-batch per-dim min/max. Straight-line: 12 independent float4
// loads issued up-front (MLP=12/thread), then compute. No loop, no atomics.
// ---------------------------------------------------------------------------
__global__ __launch_bounds__(256) void minmax_k(const float4* __restrict__ x,
                                                float* __restrict__ pmin,
                                                float* __restrict__ pmax) {
    const int b = blockIdx.x / BPB;
    const int sub = blockIdx.x % BPB;
    const float4* xb = x + (size_t)b * F4_PER_B;
    const int tid = threadIdx.x;
    const int lane = tid & 63;
    const int wv = tid >> 6;
    const int t = tid < ATH ? tid : ATH - 1;   // lanes 250..255 alias 249 (masked)

    float4 d[12];
    #pragma unroll
    for (int k = 0; k < 4; ++k) {
        int g = sub * GPB + k * ATH + t;
        d[3 * k + 0] = xb[3 * g + 0];
        d[3 * k + 1] = xb[3 * g + 1];
        d[3 * k + 2] = xb[3 * g + 2];
    }

    float mn0 = FLT_BIG, mn1 = FLT_BIG, mn2 = FLT_BIG;
    float mx0 = -FLT_BIG, mx1 = -FLT_BIG, mx2 = -FLT_BIG;
    if (tid < ATH) {
        #pragma unroll
        for (int k = 0; k < 4; ++k) {
            float4 a = d[3 * k], c = d[3 * k + 1], e = d[3 * k + 2];
            // flat%3: a.x->0 a.y->1 a.z->2 a.w->0 c.x->1 c.y->2
            //         c.z->0 c.w->1 e.x->2 e.y->0 e.z->1 e.w->2
            mn0 = fminf(mn0, fminf(fminf(a.x, a.w), fminf(c.z, e.y)));
            mx0 = fmaxf(mx0, fmaxf(fmaxf(a.x, a.w), fmaxf(c.z, e.y)));
            mn1 = fminf(mn1, fminf(fminf(a.y, c.x), fminf(c.w, e.z)));
            mx1 = fmaxf(mx1, fmaxf(fmaxf(a.y, c.x), fmaxf(c.w, e.z)));
            mn2 = fminf(mn2, fminf(fminf(a.z, c.y), fminf(e.x, e.w)));
            mx2 = fmaxf(mx2, fmaxf(fmaxf(a.z, c.y), fmaxf(e.x, e.w)));
        }
    }

    #pragma unroll
    for (int off = 32; off > 0; off >>= 1) {
        mn0 = fminf(mn0, __shfl_down(mn0, off, 64));
        mn1 = fminf(mn1, __shfl_down(mn1, off, 64));
        mn2 = fminf(mn2, __shfl_down(mn2, off, 64));
        mx0 = fmaxf(mx0, __shfl_down(mx0, off, 64));
        mx1 = fmaxf(mx1, __shfl_down(mx1, off, 64));
        mx2 = fmaxf(mx2, __shfl_down(mx2, off, 64));
    }

    __shared__ float smn[4][3], smx[4][3];
    if (lane == 0) {
        smn[wv][0] = mn0; smn[wv][1] = mn1; smn[wv][2] = mn2;
        smx[wv][0] = mx0; smx[wv][1] = mx1; smx[wv][2] = mx2;
    }
    __syncthreads();
    if (tid < 3) {
        const int dd = tid;
        float a = smn[0][dd], z = smx[0][dd];
        #pragma unroll
        for (int w = 1; w < 4; w++) {
            a = fminf(a, smn[w][dd]);
            z = fmaxf(z, smx[w][dd]);
        }
        pmin[(b * BPB + sub) * 3 + dd] = a;
        pmax[(b * BPB + sub) * 3 + dd] = z;
    }
}

// ---------------------------------------------------------------------------
// Pass 2: ballot histogram, straight-line. 12 loads in flight while waves
// 0/1 reduce the 25 min/max partials; then 16 points/thread tallied with
// zero atomics (lane L of each wave owns voxel L's count).
// ---------------------------------------------------------------------------
__device__ __forceinline__ int bin1(float v, float mn, float s4) {
    int i = (int)((v - mn) * s4);   // v>=mn, s4>0 -> trunc==floor
    return i > (VR - 1) ? (VR - 1) : i;
}

__device__ __forceinline__ void tally(int v, unsigned long long vm,
                                      const unsigned long long* ns,
                                      unsigned& cnt) {
    unsigned long long b0 = __ballot(v & 1);
    unsigned long long b1 = __ballot(v & 2);
    unsigned long long b2 = __ballot(v & 4);
    unsigned long long b3 = __ballot(v & 8);
    unsigned long long b4 = __ballot(v & 16);
    unsigned long long b5 = __ballot(v & 32);
    unsigned long long m = vm & (b0 ^ ns[0]) & (b1 ^ ns[1]) & (b2 ^ ns[2])
                              & (b3 ^ ns[3]) & (b4 ^ ns[4]) & (b5 ^ ns[5]);
    cnt += (unsigned)__popcll(m);
}

__global__ __launch_bounds__(256) void hist_k(const float4* __restrict__ x,
                                              const float* __restrict__ pmin,
                                              const float* __restrict__ pmax,
                                              unsigned* __restrict__ phist) {
    const int b = blockIdx.x / BPB;
    const int sub = blockIdx.x % BPB;
    const float4* xb = x + (size_t)b * F4_PER_B;
    const int tid = threadIdx.x;
    const int lane = tid & 63;
    const int wv = tid >> 6;
    const int t = tid < ATH ? tid : ATH - 1;

    float4 d[12];
    #pragma unroll
    for (int k = 0; k < 4; ++k) {
        int g = sub * GPB + k * ATH + t;
        d[3 * k + 0] = xb[3 * g + 0];
        d[3 * k + 1] = xb[3 * g + 1];
        d[3 * k + 2] = xb[3 * g + 2];
    }

    // reduce 25 min/max partials (waves 0/1) while x loads are in flight
    __shared__ float smm[6];   // mn0 mn1 mn2 mx0 mx1 mx2
    if (wv < 2) {
        const float* src = (wv == 0) ? pmin : pmax;
        float v0, v1, v2;
        if (lane < BPB) {
            v0 = src[(b * BPB + lane) * 3 + 0];
            v1 = src[(b * BPB + lane) * 3 + 1];
            v2 = src[(b * BPB + lane) * 3 + 2];
        } else {
            v0 = v1 = v2 = (wv == 0) ? FLT_BIG : -FLT_BIG;
        }
        #pragma unroll
        for (int off = 16; off > 0; off >>= 1) {
            float u0 = __shfl_down(v0, off, 64);
            float u1 = __shfl_down(v1, off, 64);
            float u2 = __shfl_down(v2, off, 64);
            if (wv == 0) {
                v0 = fminf(v0, u0); v1 = fminf(v1, u1); v2 = fminf(v2, u2);
            } else {
                v0 = fmaxf(v0, u0); v1 = fmaxf(v1, u1); v2 = fmaxf(v2, u2);
            }
        }
        if (lane == 0) {
            smm[wv * 3 + 0] = v0; smm[wv * 3 + 1] = v1; smm[wv * 3 + 2] = v2;
        }
    }
    __syncthreads();
    const float mn_0 = smm[0], mn_1 = smm[1], mn_2 = smm[2];
    const float s4_0 = (float)VR / (smm[3] - mn_0);
    const float s4_1 = (float)VR / (smm[4] - mn_1);
    const float s4_2 = (float)VR / (smm[5] - mn_2);

    unsigned long long ns[6];
    #pragma unroll
    for (int k = 0; k < 6; k++)
        ns[k] = ((lane >> k) & 1) ? 0ull : ~0ull;
    const unsigned long long vm = __ballot(tid < ATH);

    unsigned c_ = 0;
    #pragma unroll
    for (int k = 0; k < 4; ++k) {
        float4 a = d[3 * k], c = d[3 * k + 1], e = d[3 * k + 2];
        // points: (a.x,a.y,a.z) (a.w,c.x,c.y) (c.z,c.w,e.x) (e.y,e.z,e.w)
        int v0 = bin1(a.x, mn_0, s4_0) * 16 + bin1(a.y, mn_1, s4_1) * 4 + bin1(a.z, mn_2, s4_2);
        int v1 = bin1(a.w, mn_0, s4_0) * 16 + bin1(c.x, mn_1, s4_1) * 4 + bin1(c.y, mn_2, s4_2);
        int v2 = bin1(c.z, mn_0, s4_0) * 16 + bin1(c.w, mn_1, s4_1) * 4 + bin1(e.x, mn_2, s4_2);
        int v3 = bin1(e.y, mn_0, s4_0) * 16 + bin1(e.z, mn_1, s4_1) * 4 + bin1(e.w, mn_2, s4_2);
        tally(v0, vm, ns, c_);
        tally(v1, vm, ns, c_);
        tally(v2, vm, ns, c_);
        tally(v3, vm, ns, c_);
    }

    __shared__ unsigned swh[4][NVOX];
    swh[wv][lane] = c_;
    __syncthreads();
    if (tid < NVOX) {
        phist[(b * BPB + sub) * NVOX + tid] =
            swh[0][tid] + swh[1][tid] + swh[2][tid] + swh[3][tid];
    }
}

// ---------------------------------------------------------------------------
// Pass 3: reduce the 25 hist partials per batch + 40x64 GEMV, one block/batch.
// ---------------------------------------------------------------------------
__global__ __launch_bounds__(256) void gemv_k(const unsigned* __restrict__ phist,
                                              const float* __restrict__ W,
                                              const float* __restrict__ bias,
                                              float* __restrict__ out) {
    const int b = blockIdx.x;
    __shared__ float fh[NVOX];
    __shared__ float sW[NCLS * NVOX];

    if (threadIdx.x < NVOX) {
        unsigned s = 0;
        for (int p = 0; p < BPB; p++)
            s += phist[(b * BPB + p) * NVOX + threadIdx.x];
        fh[threadIdx.x] = (float)s * (1.0f / (float)NPTS);
    }
    for (int i = threadIdx.x; i < NCLS * NVOX; i += 256)
        sW[i] = W[i];
    __syncthreads();

    if (threadIdx.x < NCLS) {
        const int c = threadIdx.x;
        float acc = 0.f;
        #pragma unroll
        for (int f = 0; f < NVOX; f++)
            acc += fh[f] * sW[c * NVOX + f];
        out[b * NCLS + c] = acc + bias[c];
    }
}

extern "C" void kernel_launch(void* const* d_in, const int* in_sizes, int n_in,
                              void* d_out, int out_size, void* d_ws, size_t ws_size,
                              hipStream_t stream) {
    const float* x = (const float*)d_in[0];      // (64, 100000, 3) fp32
    const float* W = (const float*)d_in[1];      // (40, 64) fp32
    const float* bias = (const float*)d_in[2];   // (40,) fp32
    float* out = (float*)d_out;                  // (64, 40) fp32

    // ws layout (all slots fully overwritten every call -> no init needed):
    //   pmin  : NB*BPB*3 f32
    //   pmax  : NB*BPB*3 f32
    //   phist : NB*BPB*64 u32
    float* pmin = (float*)d_ws;
    float* pmax = pmin + NB * BPB * 3;
    unsigned* phist = (unsigned*)(pmax + NB * BPB * 3);

    minmax_k<<<NB * BPB, 256, 0, stream>>>((const float4*)x, pmin, pmax);
    hist_k<<<NB * BPB, 256, 0, stream>>>((const float4*)x, pmin, pmax, phist);
    gemv_k<<<NB, 256, 0, stream>>>(phist, W, bias, out);
}